// Round 14
// baseline (136.909 us; speedup 1.0000x reference)
//
#include <hip/hip_runtime.h>

// Additive attention, factored:
//   scores'[b,q,k] = sum_h (-2 w_h) / (1 + Eq[b,q,h]*Ek[b,k,h]),  Eq=e^{2qp}, Ek=e^{2kp}
// (constant sum_h w_h cancels in softmax). 4-way reciprocal grouping over h.
// Range safety: A..E in [1, ~2e8] -> AB*CE <= ~2e33 < FLT_MAX.
//
// Round-14 (v12): discriminating test of the L1-line-miss model. Across 11
// variants, time tracks per-CU DISTINCT 128B lines missed (~10cy/line TCP
// processing), not traffic/occupancy/load-count. v12: 8 q per block, grid 256
// = 1 block/CU -> per-CU lines HALVE vs v10 (4096 vs 8192) while per-CU
// load-instruction count is IDENTICAL to v10 (16 waves x 128 dword loads).
// Line-model -> fused ~30; instr-model -> unchanged ~43 (then: roofline).

#define Bb 8
#define Qn 256
#define Kk 1024
#define Dd 256
#define Hh 128
#define DVv 128

__device__ __forceinline__ float fexp2(float x) { return __builtin_amdgcn_exp2f(x); }
__device__ __forceinline__ float frcp(float x)  { return __builtin_amdgcn_rcpf(x); }

// ---------------------------------------------------------------------------
// K0: W [H][D] -> W4T [D/4][H] float4. 64 blocks x 256 threads.
// ---------------------------------------------------------------------------
__global__ __launch_bounds__(256)
void repack_w(const float* __restrict__ Wq, const float* __restrict__ Wk,
              float4* __restrict__ Wq4T, float4* __restrict__ Wk4T)
{
    const int blk = blockIdx.x;
    const float* src = (blk < 32) ? Wq : Wk;
    float4*      dst = (blk < 32) ? Wq4T : Wk4T;
    const int idx = (blk & 31) * 256 + threadIdx.x;   // 8192 float4 per matrix
    const int g = idx >> 7;          // d-group 0..63
    const int h = idx & 127;
    dst[idx] = *(const float4*)(src + (size_t)h * Dd + g * 4);
}

// ---------------------------------------------------------------------------
// K1: EqT[b][h][r] = exp2(2*log2e * X[r]·W[h]). 640 blocks x 512 threads.
// ---------------------------------------------------------------------------
__global__ __launch_bounds__(512)
void proj_exp_kernel(const float* __restrict__ queries,
                     const float* __restrict__ keys,
                     const float4* __restrict__ Wq4T,
                     const float4* __restrict__ Wk4T,
                     float* __restrict__ EqT,
                     float* __restrict__ EkT)
{
    __shared__ __align__(16) float Xs[16 * 256];     // 16 KB
    const int blk = blockIdx.x;                  // 0..127 queries, 128..639 keys
    const float* X; const float4* W4; float* outT; int RB; int i0;
    if (blk < 128) { X = queries; W4 = Wq4T; outT = EqT; RB = Qn; i0 = blk * 16; }
    else           { X = keys;    W4 = Wk4T; outT = EkT; RB = Kk; i0 = (blk - 128) * 16; }
    const int tid = threadIdx.x;
    const int h   = tid & 127;
    const int r4  = __builtin_amdgcn_readfirstlane(tid >> 7);   // 0..3, wave-uniform

    {   // stage 16x256 X tile, coalesced float4
        const float4* xsrc = (const float4*)(X + (size_t)i0 * Dd);
#pragma unroll
        for (int s = 0; s < 2; ++s) {
            const int idx = tid + 512 * s;       // 1024 float4
            *(float4*)(Xs + idx * 4) = xsrc[idx];
        }
    }
    __syncthreads();

    float acc[4] = {0.f, 0.f, 0.f, 0.f};
    const float4* wp = W4 + h;                   // stride 128 float4 per group
    const float*  xr = Xs + (r4 * 4) * 256;
#pragma unroll 8
    for (int g = 0; g < 64; ++g) {
        const float4 w = wp[(size_t)g * 128];    // coalesced dwordx4
#pragma unroll
        for (int i = 0; i < 4; ++i) {
            const float4 x = *(const float4*)(xr + i * 256 + g * 4);  // broadcast b128
            acc[i] = fmaf(x.x, w.x, acc[i]);
            acc[i] = fmaf(x.y, w.y, acc[i]);
            acc[i] = fmaf(x.z, w.z, acc[i]);
            acc[i] = fmaf(x.w, w.w, acc[i]);
        }
    }
    const int b    = i0 / RB;                    // 16 | RB, never straddles b
    const int rloc = (i0 % RB) + r4 * 4;
    float4 o;
    o.x = fexp2(acc[0] * 2.885390082f);          // e^{2x} = 2^{2x*log2e}
    o.y = fexp2(acc[1] * 2.885390082f);
    o.z = fexp2(acc[2] * 2.885390082f);
    o.w = fexp2(acc[3] * 2.885390082f);
    *(float4*)(outT + (size_t)b * Hh * RB + (size_t)h * RB + rloc) = o;
}

// score update for one (q, k) at 4 h: 14 VALU + 1 rcp
#define SCORE4(q4, w4, ea, eb, ec, ed, accref)                                \
    {                                                                          \
        const float A_ = fmaf((q4).x, (ea), 1.f), B_ = fmaf((q4).y, (eb), 1.f);\
        const float C_ = fmaf((q4).z, (ec), 1.f), E_ = fmaf((q4).w, (ed), 1.f);\
        const float AB_ = A_ * B_, CE_ = C_ * E_;                              \
        const float N_ = fmaf(fmaf((w4).x, B_, (w4).y * A_), CE_,              \
                              fmaf((w4).z, E_, (w4).w * C_) * AB_);            \
        (accref) = fmaf(N_, frcp(AB_ * CE_), (accref));                        \
    }

// ---------------------------------------------------------------------------
// K23 fused v12: grid 256 (qt<<3 | b), 1024 threads (16 waves), 1 block/CU.
// Thread = 1 k (tid) x 8 q x 128 h: 128 dword loads/thread, each (h,k) line
//   touched by exactly one block per CU. acc[8]; direct s_sc write (no merge).
// Wave k-span = 64: wave-uniform skip when span >= len.
// Phase 2: softmax, 16 waves: q = wave&7, half = wave>>3 (512 k each).
// Phase 3: P@V, 32 k-slices x 32 v-lanes x float4; 16-wave fold via s_part.
// LDS: 32K s_sc + 4K eqsT + 0.5K w2s + 61.4K s_part ~= 98 KB -> 1 block/CU.
// ---------------------------------------------------------------------------
__global__ __launch_bounds__(1024, 4)
void score_softmax_pv_kernel(const float* __restrict__ EqT,
                             const float* __restrict__ EkT,
                             const float* __restrict__ wv,
                             const int* __restrict__ valid_lens,
                             const float* __restrict__ values,
                             float* __restrict__ out)
{
    __shared__ __align__(16) float  s_sc[8][Kk];        // 32 KB
    __shared__ __align__(16) float  eqsT[8][Hh];        // 4 KB  [q][h]
    __shared__ __align__(16) float  w2s[Hh];            // 0.5 KB
    __shared__ __align__(16) float4 s_part[15][8][32];  // 61.4 KB
    __shared__ float s_qmax[8][2];
    __shared__ float s_qsum[8][2];

    const int blk  = blockIdx.x;
    const int b    = blk & 7;                     // b fastest (XCD spread)
    const int qt   = blk >> 3;                    // 0..31
    const int q0   = qt * 8;
    const int len  = valid_lens[b];
    const int tid  = threadIdx.x;
    const int lane = tid & 63;
    const int wave = __builtin_amdgcn_readfirstlane(tid >> 6);   // 0..15

    // ---- stage eqT (transposed: [q][h]) and -2*wv
    if (tid < 128) {
        const float4 v0 = *(const float4*)(EqT + (size_t)b * Hh * Qn + (size_t)tid * Qn + q0);
        const float4 v1 = *(const float4*)(EqT + (size_t)b * Hh * Qn + (size_t)tid * Qn + q0 + 4);
        eqsT[0][tid] = v0.x; eqsT[1][tid] = v0.y; eqsT[2][tid] = v0.z; eqsT[3][tid] = v0.w;
        eqsT[4][tid] = v1.x; eqsT[5][tid] = v1.y; eqsT[6][tid] = v1.z; eqsT[7][tid] = v1.w;
    } else if (tid < 256) {
        w2s[tid - 128] = -2.0f * wv[tid - 128];
    }
    __syncthreads();

    // ---- phase 1: scores for 8 q x 1 k per thread (k = tid)
    {
        const int kspan = (tid >> 6) << 6;        // wave's 64-k base
        if (kspan < len) {                        // wave-uniform skip (tail unread)
            const float* ekp = EkT + (size_t)b * Hh * Kk + tid;
            float acc[8] = {};
#pragma unroll 2
            for (int hg = 0; hg < 32; ++hg) {
                const int h = hg << 2;
                const float e0 = ekp[(size_t)(h + 0) * Kk];   // coalesced dwords
                const float e1 = ekp[(size_t)(h + 1) * Kk];
                const float e2 = ekp[(size_t)(h + 2) * Kk];
                const float e3 = ekp[(size_t)(h + 3) * Kk];
                const float4 w4 = *(const float4*)(w2s + h);  // LDS broadcast b128
#pragma unroll
                for (int q = 0; q < 8; ++q) {
                    const float4 q4 = *(const float4*)(&eqsT[q][h]);
                    SCORE4(q4, w4, e0, e1, e2, e3, acc[q]);
                }
            }
#pragma unroll
            for (int q = 0; q < 8; ++q) s_sc[q][tid] = acc[q];   // stride-1: free
        }
    }
    __syncthreads();

    // ---- phase 2: masked softmax, 16 waves: q = wave&7, half = wave>>3
    {
        const int q    = wave & 7;
        const int half = wave >> 3;
        const int base = half * 512;
        const int hi   = (base + 512 < len) ? base + 512 : len;
        float m = -3.0e38f;
        for (int i = base + lane; i < hi; i += 64) m = fmaxf(m, s_sc[q][i]);
#pragma unroll
        for (int off = 32; off > 0; off >>= 1) m = fmaxf(m, __shfl_xor(m, off));
        if (lane == 0) s_qmax[q][half] = m;
        __syncthreads();
        const float gm = fmaxf(s_qmax[q][0], s_qmax[q][1]);
        float sum = 0.f;
        for (int i = base + lane; i < hi; i += 64) {
            const float p = fexp2((s_sc[q][i] - gm) * 1.44269504f);
            s_sc[q][i] = p;
            sum += p;
        }
#pragma unroll
        for (int off = 32; off > 0; off >>= 1) sum += __shfl_xor(sum, off);
        if (lane == 0) s_qsum[q][half] = sum;
    }
    __syncthreads();

    // ---- phase 3: P@V, 32 k-slices x (32 lanes x float4 = 128 v), 8 q rows
    {
        const int slice = tid >> 5;               // 0..31
        const int l32   = tid & 31;
        const int v4    = l32 << 2;
        const float* vp = values + (size_t)b * Kk * DVv + v4;
        float a[8][4];
#pragma unroll
        for (int q = 0; q < 8; ++q) { a[q][0]=0.f; a[q][1]=0.f; a[q][2]=0.f; a[q][3]=0.f; }
        for (int k = slice; k < len; k += 32) {
            const float4 val = *(const float4*)(vp + (size_t)k * DVv);
#pragma unroll
            for (int q = 0; q < 8; ++q) {
                const float w = s_sc[q][k];
                a[q][0] = fmaf(w, val.x, a[q][0]);
                a[q][1] = fmaf(w, val.y, a[q][1]);
                a[q][2] = fmaf(w, val.z, a[q][2]);
                a[q][3] = fmaf(w, val.w, a[q][3]);
            }
        }
        // fold the two slices within each wave (slice 2w | 2w+1)
#pragma unroll
        for (int q = 0; q < 8; ++q)
#pragma unroll
            for (int x = 0; x < 4; ++x) a[q][x] += __shfl_xor(a[q][x], 32);
        if (wave > 0 && lane < 32) {
#pragma unroll
            for (int q = 0; q < 8; ++q)
                s_part[wave - 1][q][l32] = make_float4(a[q][0], a[q][1], a[q][2], a[q][3]);
        }
        __syncthreads();
        if (wave == 0 && lane < 32) {
#pragma unroll
            for (int q = 0; q < 8; ++q) {
                float r0 = a[q][0], r1 = a[q][1], r2 = a[q][2], r3 = a[q][3];
#pragma unroll
                for (int w = 0; w < 15; ++w) {
                    const float4 p = s_part[w][q][l32];
                    r0 += p.x; r1 += p.y; r2 += p.z; r3 += p.w;
                }
                const float inv = frcp(s_qsum[q][0] + s_qsum[q][1]);
                *(float4*)(out + (size_t)(b * Qn + q0 + q) * DVv + v4) =
                    make_float4(r0 * inv, r1 * inv, r2 * inv, r3 * inv);
            }
        }
    }
}

extern "C" void kernel_launch(void* const* d_in, const int* in_sizes, int n_in,
                              void* d_out, int out_size, void* d_ws, size_t ws_size,
                              hipStream_t stream) {
    (void)in_sizes; (void)n_in; (void)out_size; (void)ws_size;
    const float* queries    = (const float*)d_in[0];
    const float* keys       = (const float*)d_in[1];
    const float* values     = (const float*)d_in[2];
    const int*   valid_lens = (const int*)  d_in[3];
    const float* Wq         = (const float*)d_in[4];
    const float* Wk         = (const float*)d_in[5];
    const float* wvv        = (const float*)d_in[6];
    float* out = (float*)d_out;

    float* Wq4T = (float*)d_ws;                                  // 256*128 floats
    float* Wk4T = Wq4T + (size_t)Dd * Hh;
    float* EqT  = Wk4T + (size_t)Dd * Hh;                        // 8*128*256
    float* EkT  = EqT + (size_t)Bb * Hh * Qn;                    // 8*128*1024

    repack_w       <<<  64, 256, 0, stream>>>(Wq, Wk, (float4*)Wq4T, (float4*)Wk4T);
    proj_exp_kernel<<< 640, 512, 0, stream>>>(queries, keys, (const float4*)Wq4T,
                                              (const float4*)Wk4T, EqT, EkT);
    score_softmax_pv_kernel<<<256, 1024, 0, stream>>>(EqT, EkT, wvv, valid_lens,
                                                      values, out);
}